// Round 1
// baseline (333.300 us; speedup 1.0000x reference)
//
#include <hip/hip_runtime.h>
#include <stdint.h>

#define B_ 32
#define T_ 4096
#define D_ 512
#define BT_ (B_*T_)

typedef __attribute__((ext_vector_type(8))) short bf16x8;
typedef __attribute__((ext_vector_type(4))) float f32x4;

__device__ __forceinline__ unsigned short f2bf(float f) {
    unsigned int u = __float_as_uint(f);
    u += 0x7FFFu + ((u >> 16) & 1u);   // round-to-nearest-even (inputs are finite)
    return (unsigned short)(u >> 16);
}

// ---------------------------------------------------------------------------
// W_h (D x D fp32, [k][n]) -> bf16 MFMA B-fragment layout in ws:
//   wsb[((nt*16+kt)*64 + l)*8 + j] = bf16(W_h[kt*32 + (l>>4)*8 + j][nt*16 + (l&15)])
// 32768 threads, one 16B fragment slice per thread.
__global__ __launch_bounds__(256) void k_conv_wh(const float* __restrict__ W_h,
                                                 unsigned short* __restrict__ wsb) {
    int tid = blockIdx.x * 256 + threadIdx.x;   // 0..32767
    int l  = tid & 63;
    int kt = (tid >> 6) & 15;
    int nt = tid >> 10;
    int n  = nt * 16 + (l & 15);
    int k0 = kt * 32 + (l >> 4) * 8;
    unsigned int w[4];
#pragma unroll
    for (int q = 0; q < 4; ++q) {
        unsigned short lo = f2bf(W_h[(size_t)(k0 + 2*q)     * D_ + n]);
        unsigned short hi = f2bf(W_h[(size_t)(k0 + 2*q + 1) * D_ + n]);
        w[q] = (unsigned int)lo | ((unsigned int)hi << 16);
    }
    uint4 pk = {w[0], w[1], w[2], w[3]};
    ((uint4*)wsb)[tid] = pk;
}

// ---------------------------------------------------------------------------
// dec[b][c] = b_s[c] + sum_k s_t[b][k] * W_s[k][c]   (32 x 512, tiny GEMM)
__global__ __launch_bounds__(256) void k_dec(const float* __restrict__ s_t,
                                             const float* __restrict__ W_s,
                                             const float* __restrict__ b_s,
                                             float* __restrict__ dec) {
    int b = blockIdx.x;
    int c = threadIdx.x;
    float a0 = b_s[c], a1 = b_s[c + 256];
    const float* srow = s_t + b * D_;
    for (int k = 0; k < D_; ++k) {
        float s = srow[k];
        const float* wr = W_s + (size_t)k * D_;
        a0 = fmaf(s, wr[c], a0);
        a1 = fmaf(s, wr[c + 256], a1);
    }
    dec[b * D_ + c] = a0;
    dec[b * D_ + c + 256] = a1;
}

// ---------------------------------------------------------------------------
// Main fused kernel: e[b][t] = sum_n tanh( (h W_h)[t][n] + dec[b][n] + cov[b][t]*W_c[n] ) * V[n]
// Block = 4 waves x 16 rows = 64 rows of the flattened (B*T) dimension.
// A panel per wave in LDS (bf16, XOR-swizzled); B fragments from pre-swizzled ws (L2-hot).
__global__ __launch_bounds__(256, 2) void k_main(const float* __restrict__ h_i,
                                                 const float* __restrict__ coverage,
                                                 const unsigned short* __restrict__ wsb,
                                                 const float* __restrict__ dec,
                                                 const float* __restrict__ W_c,
                                                 const float* __restrict__ V,
                                                 float* __restrict__ e_out) {
    __shared__ __align__(16) unsigned char lds[65536];
    const int tid = threadIdx.x;
    const int w = tid >> 6, l = tid & 63;
    const int row0 = blockIdx.x * 64;           // flat row (b*T + t), tile-aligned within batch
    const int b    = row0 >> 12;                // / T_
    const int t0w  = (row0 & (T_ - 1)) + w * 16;
    const size_t rbase = (size_t)(row0 + w * 16) * D_;

    unsigned char* As = lds + w * 16384;        // per-wave 16 rows x 512 k, bf16

    // ---- stage A: 16 rows, fp32 -> bf16, swizzled LDS write
#pragma unroll 4
    for (int i = 0; i < 16; ++i) {
        const float* src = h_i + rbase + (size_t)i * D_ + l * 8;
        float4 f0 = *(const float4*)(src);
        float4 f1 = *(const float4*)(src + 4);
        uint4 pk;
        pk.x = (unsigned)f2bf(f0.x) | ((unsigned)f2bf(f0.y) << 16);
        pk.y = (unsigned)f2bf(f0.z) | ((unsigned)f2bf(f0.w) << 16);
        pk.z = (unsigned)f2bf(f1.x) | ((unsigned)f2bf(f1.y) << 16);
        pk.w = (unsigned)f2bf(f1.z) | ((unsigned)f2bf(f1.w) << 16);
        int byte = (i * 1024 + l * 16) ^ ((i & 7) << 4);
        *(uint4*)(As + byte) = pk;
    }
    __syncthreads();

    // per-lane coverage for its 4 C-rows (row = (l>>4)*4 + r)
    const int rgrp = (l >> 4) * 4;
    float cov_r[4];
#pragma unroll
    for (int r = 0; r < 4; ++r) cov_r[r] = coverage[b * T_ + t0w + rgrp + r];

    const int arow   = l & 15;
    const int abyte0 = arow * 1024 + (l >> 4) * 16;   // + kt*64 per K-step
    const int aswz   = (arow & 7) << 4;

    float p[4] = {0.f, 0.f, 0.f, 0.f};
    const uint4* bp = (const uint4*)wsb;

    for (int nc = 0; nc < 8; ++nc) {            // 8 chunks of 64 output features
        f32x4 acc[4] = {{0,0,0,0},{0,0,0,0},{0,0,0,0},{0,0,0,0}};
#pragma unroll 4
        for (int kt = 0; kt < 16; ++kt) {       // K = 512 in steps of 32
            int abyte = (abyte0 + kt * 64) ^ aswz;
            uint4 araw = *(const uint4*)(As + abyte);
            bf16x8 a = __builtin_bit_cast(bf16x8, araw);
#pragma unroll
            for (int j = 0; j < 4; ++j) {
                int nt = nc * 4 + j;
                uint4 braw = bp[(nt * 16 + kt) * 64 + l];
                bf16x8 bv = __builtin_bit_cast(bf16x8, braw);
                acc[j] = __builtin_amdgcn_mfma_f32_16x16x32_bf16(a, bv, acc[j], 0, 0, 0);
            }
        }
        // epilogue: tanh + dot with V, accumulate per-row partials
#pragma unroll
        for (int j = 0; j < 4; ++j) {
            int col = (nc * 4 + j) * 16 + (l & 15);
            float dv = dec[b * D_ + col];
            float wc = W_c[col];
            float vv = V[col];
#pragma unroll
            for (int r = 0; r < 4; ++r) {
                float x = acc[j][r] + dv + cov_r[r] * wc;
                p[r] += tanhf(x) * vv;
            }
        }
    }

    // reduce across the 16 lanes sharing each row (lane bits 0..3)
#pragma unroll
    for (int m = 1; m <= 8; m <<= 1) {
#pragma unroll
        for (int r = 0; r < 4; ++r) p[r] += __shfl_xor(p[r], m, 64);
    }
    if ((l & 15) == 0) {
#pragma unroll
        for (int r = 0; r < 4; ++r)
            e_out[b * T_ + t0w + rgrp + r] = p[r];
    }
}

// ---------------------------------------------------------------------------
// Softmax over T per batch + new_coverage. e lives in the a_t output slot
// (each thread reads its own elems into regs before overwriting -> safe).
__global__ __launch_bounds__(256) void k_soft(const float* __restrict__ e_in,
                                              const float* __restrict__ coverage,
                                              float* __restrict__ out_at,
                                              float* __restrict__ out_cov) {
    int b = blockIdx.x, tid = threadIdx.x;
    __shared__ float red[4];
    float v[16];
    float m = -1e30f;
#pragma unroll
    for (int i = 0; i < 16; ++i) {
        v[i] = e_in[b * T_ + tid + i * 256];
        m = fmaxf(m, v[i]);
    }
#pragma unroll
    for (int mk = 1; mk <= 32; mk <<= 1) m = fmaxf(m, __shfl_xor(m, mk, 64));
    if ((tid & 63) == 0) red[tid >> 6] = m;
    __syncthreads();
    m = fmaxf(fmaxf(red[0], red[1]), fmaxf(red[2], red[3]));
    float s = 0.f;
#pragma unroll
    for (int i = 0; i < 16; ++i) { v[i] = expf(v[i] - m); s += v[i]; }
#pragma unroll
    for (int mk = 1; mk <= 32; mk <<= 1) s += __shfl_xor(s, mk, 64);
    __syncthreads();
    if ((tid & 63) == 0) red[tid >> 6] = s;
    __syncthreads();
    s = red[0] + red[1] + red[2] + red[3];
    float inv = 1.0f / s;
#pragma unroll
    for (int i = 0; i < 16; ++i) {
        int idx = b * T_ + tid + i * 256;
        float a = v[i] * inv;
        out_at[idx]  = a;
        out_cov[idx] = coverage[idx] + a;
    }
}

// ---------------------------------------------------------------------------
// context partials: block (b, s) handles 64 timesteps, 512 dims.
// part[(b*64+s)*512 + d] = sum_{t in chunk} a_t[b][t] * h_i[b][t][d]
__global__ __launch_bounds__(256) void k_ctx(const float* __restrict__ h_i,
                                             const float* __restrict__ a_t,
                                             float* __restrict__ part) {
    int blk = blockIdx.x;           // 0..2047
    int b = blk >> 6, s = blk & 63;
    int d0 = threadIdx.x * 2;
    const size_t base = ((size_t)b * T_ + (size_t)s * 64) * D_;
    const float* at = a_t + b * T_ + s * 64;
    float2 acc = {0.f, 0.f};
    for (int t = 0; t < 64; ++t) {
        float a = at[t];
        float2 h2 = *(const float2*)(h_i + base + (size_t)t * D_ + d0);
        acc.x = fmaf(a, h2.x, acc.x);
        acc.y = fmaf(a, h2.y, acc.y);
    }
    float* pp = part + (size_t)blk * D_ + d0;
    pp[0] = acc.x;
    pp[1] = acc.y;
}

// combine: context[b][d] = sum_s part[(b*64+s)*512 + d]  (deterministic)
__global__ __launch_bounds__(256) void k_comb(const float* __restrict__ part,
                                              float* __restrict__ out_ctx) {
    int idx = blockIdx.x * 256 + threadIdx.x;   // 0..16383
    int b = idx >> 9, d = idx & 511;
    const float* pp = part + (size_t)b * 64 * D_ + d;
    float s = 0.f;
#pragma unroll 8
    for (int j = 0; j < 64; ++j) s += pp[(size_t)j * D_];
    out_ctx[idx] = s;
}

// ---------------------------------------------------------------------------
extern "C" void kernel_launch(void* const* d_in, const int* in_sizes, int n_in,
                              void* d_out, int out_size, void* d_ws, size_t ws_size,
                              hipStream_t stream) {
    const float* h_i      = (const float*)d_in[0];
    const float* s_t      = (const float*)d_in[1];
    const float* coverage = (const float*)d_in[2];
    const float* W_h      = (const float*)d_in[3];
    const float* W_s      = (const float*)d_in[4];
    const float* b_s      = (const float*)d_in[5];
    const float* W_c      = (const float*)d_in[6];
    const float* V        = (const float*)d_in[7];

    float* out_ctx = (float*)d_out;             // B*D
    float* out_at  = out_ctx + B_ * D_;         // B*T (holds e_t between k_main and k_soft)
    float* out_cov = out_at + BT_;              // B*T

    unsigned short* wsb = (unsigned short*)d_ws;              // 512 KB bf16 W_h frags
    float* dec  = (float*)((char*)d_ws + 524288);             // 64 KB
    float* part = dec + B_ * D_;                              // 32*64*512 fp32 = 4 MB

    k_conv_wh<<<128, 256, 0, stream>>>(W_h, wsb);
    k_dec<<<B_, 256, 0, stream>>>(s_t, W_s, b_s, dec);
    k_main<<<BT_ / 64, 256, 0, stream>>>(h_i, coverage, wsb, dec, W_c, V, out_at);
    k_soft<<<B_, 256, 0, stream>>>(out_at, coverage, out_at, out_cov);
    k_ctx<<<B_ * 64, 256, 0, stream>>>(h_i, out_at, part);
    k_comb<<<B_ * D_ / 256, 256, 0, stream>>>(part, out_ctx);
}

// Round 2
// 204.071 us; speedup vs baseline: 1.6332x; 1.6332x over previous
//
#include <hip/hip_runtime.h>
#include <stdint.h>

#define B_ 32
#define T_ 4096
#define D_ 512
#define BT_ (B_*T_)

typedef __attribute__((ext_vector_type(8))) short bf16x8;
typedef __attribute__((ext_vector_type(4))) float f32x4;

__device__ __forceinline__ unsigned short f2bf(float f) {
    unsigned int u = __float_as_uint(f);
    u += 0x7FFFu + ((u >> 16) & 1u);   // round-to-nearest-even (inputs are finite)
    return (unsigned short)(u >> 16);
}

__device__ __forceinline__ float tanh_fast(float x) {
    float e2 = __expf(2.0f * x);       // inf for large x, 0 for very negative -> correct limits
    return 1.0f - 2.0f / (e2 + 1.0f);
}

// ---------------------------------------------------------------------------
// W_h (D x D fp32, [k][n]) -> bf16 MFMA B-fragment layout in ws:
//   wsb[((nt*16+kt)*64 + l)*8 + j] = bf16(W_h[kt*32 + (l>>4)*8 + j][nt*16 + (l&15)])
__global__ __launch_bounds__(256) void k_conv_wh(const float* __restrict__ W_h,
                                                 unsigned short* __restrict__ wsb) {
    int tid = blockIdx.x * 256 + threadIdx.x;   // 0..32767
    int l  = tid & 63;
    int kt = (tid >> 6) & 15;
    int nt = tid >> 10;
    int n  = nt * 16 + (l & 15);
    int k0 = kt * 32 + (l >> 4) * 8;
    unsigned int w[4];
#pragma unroll
    for (int q = 0; q < 4; ++q) {
        unsigned short lo = f2bf(W_h[(size_t)(k0 + 2*q)     * D_ + n]);
        unsigned short hi = f2bf(W_h[(size_t)(k0 + 2*q + 1) * D_ + n]);
        w[q] = (unsigned int)lo | ((unsigned int)hi << 16);
    }
    uint4 pk = {w[0], w[1], w[2], w[3]};
    ((uint4*)wsb)[tid] = pk;
}

// ---------------------------------------------------------------------------
// dec[b][c] = b_s[c] + sum_k s_t[b][k] * W_s[k][c]
__global__ __launch_bounds__(256) void k_dec(const float* __restrict__ s_t,
                                             const float* __restrict__ W_s,
                                             const float* __restrict__ b_s,
                                             float* __restrict__ dec) {
    int b = blockIdx.x;
    int c = threadIdx.x;
    float a0 = b_s[c], a1 = b_s[c + 256];
    const float* srow = s_t + b * D_;
    for (int k = 0; k < D_; ++k) {
        float s = srow[k];
        const float* wr = W_s + (size_t)k * D_;
        a0 = fmaf(s, wr[c], a0);
        a1 = fmaf(s, wr[c + 256], a1);
    }
    dec[b * D_ + c] = a0;
    dec[b * D_ + c + 256] = a1;
}

// ---------------------------------------------------------------------------
// Main fused kernel. Block = 64 rows of (B*T), 4 waves.
// A panel (64 rows x 512 K, bf16) staged ONCE in LDS in fragment-linear order,
// shared by all 4 waves. Wave w computes output cols [w*128, w*128+128).
// LDS layout: frag (af in 0..3, kt in 0..15) at (af*16+kt)*1024; within frag,
// lane slot = (lane ^ (kt&7))*16  -- XOR spreads staging-write banks, reads
// use the same involution (both-sides rule).
__global__ __launch_bounds__(256, 2) void k_main(const float* __restrict__ h_i,
                                                 const float* __restrict__ coverage,
                                                 const unsigned short* __restrict__ wsb,
                                                 const float* __restrict__ dec,
                                                 const float* __restrict__ W_c,
                                                 const float* __restrict__ V,
                                                 float* __restrict__ e_out) {
    __shared__ __align__(16) unsigned char As[65536];
    __shared__ float red[4][64];
    const int tid = threadIdx.x;
    const int w = tid >> 6, l = tid & 63;
    const int row0 = blockIdx.x * 64;           // flat (b*T + t), 64-aligned
    const int b    = row0 >> 12;
    const int t0   = row0 & (T_ - 1);

    // ---- stage A: 64 rows x 512 k, fp32 -> bf16, fragment-linear + XOR slot
#pragma unroll
    for (int i = 0; i < 16; ++i) {
        int idx = i * 256 + tid;                // 0..4095
        int row = idx >> 6;                     // 0..63
        int c   = idx & 63;                     // 8-elem chunk within row
        const float* src = h_i + (size_t)(row0 + row) * D_ + c * 8;
        float4 f0 = *(const float4*)(src);
        float4 f1 = *(const float4*)(src + 4);
        uint4 pk;
        pk.x = (unsigned)f2bf(f0.x) | ((unsigned)f2bf(f0.y) << 16);
        pk.y = (unsigned)f2bf(f0.z) | ((unsigned)f2bf(f0.w) << 16);
        pk.z = (unsigned)f2bf(f1.x) | ((unsigned)f2bf(f1.y) << 16);
        pk.w = (unsigned)f2bf(f1.z) | ((unsigned)f2bf(f1.w) << 16);
        int kt   = c >> 2;
        int lane = (row & 15) + 16 * (c & 3);
        int byte = (((row >> 4) * 16 + kt) << 10) + ((lane ^ (kt & 7)) << 4);
        *(uint4*)(As + byte) = pk;
    }
    __syncthreads();

    // per-lane coverage for the 16 C-rows this lane produces
    const int rgrp = (l >> 4) * 4;
    float cov_r[4][4];
#pragma unroll
    for (int af = 0; af < 4; ++af)
#pragma unroll
        for (int r = 0; r < 4; ++r)
            cov_r[af][r] = coverage[b * T_ + t0 + af * 16 + rgrp + r];

    float p[4][4] = {{0,0,0,0},{0,0,0,0},{0,0,0,0},{0,0,0,0}};  // [af][r]
    const uint4* bp = (const uint4*)wsb;

    for (int half = 0; half < 2; ++half) {
        const int nc = w * 2 + half;            // 0..7 : cols nc*64..+64
        f32x4 acc[4][4];                        // [af][j]
#pragma unroll
        for (int af = 0; af < 4; ++af)
#pragma unroll
            for (int j = 0; j < 4; ++j) acc[af][j] = (f32x4){0,0,0,0};

#pragma unroll 4
        for (int kt = 0; kt < 16; ++kt) {
            bf16x8 bv[4];
#pragma unroll
            for (int j = 0; j < 4; ++j) {
                uint4 braw = bp[(((nc * 4 + j) * 16 + kt) << 6) + l];
                bv[j] = __builtin_bit_cast(bf16x8, braw);
            }
#pragma unroll
            for (int af = 0; af < 4; ++af) {
                int byte = ((af * 16 + kt) << 10) + (((l ^ (kt & 7))) << 4);
                uint4 araw = *(const uint4*)(As + byte);
                bf16x8 a = __builtin_bit_cast(bf16x8, araw);
#pragma unroll
                for (int j = 0; j < 4; ++j)
                    acc[af][j] = __builtin_amdgcn_mfma_f32_16x16x32_bf16(a, bv[j], acc[af][j], 0, 0, 0);
            }
        }
        // epilogue: tanh + dot with V for this 64-col chunk
#pragma unroll
        for (int j = 0; j < 4; ++j) {
            int col = nc * 64 + j * 16 + (l & 15);
            float dv = dec[b * D_ + col];
            float wc = W_c[col];
            float vv = V[col];
#pragma unroll
            for (int af = 0; af < 4; ++af)
#pragma unroll
                for (int r = 0; r < 4; ++r) {
                    float x = acc[af][j][r] + dv + cov_r[af][r] * wc;
                    p[af][r] += tanh_fast(x) * vv;
                }
        }
    }

    // reduce across the 16 lanes sharing each row
#pragma unroll
    for (int m = 1; m <= 8; m <<= 1)
#pragma unroll
        for (int af = 0; af < 4; ++af)
#pragma unroll
            for (int r = 0; r < 4; ++r)
                p[af][r] += __shfl_xor(p[af][r], m, 64);
    if ((l & 15) == 0) {
#pragma unroll
        for (int af = 0; af < 4; ++af)
#pragma unroll
            for (int r = 0; r < 4; ++r)
                red[w][af * 16 + rgrp + r] = p[af][r];
    }
    __syncthreads();
    if (tid < 64) {
        float e = red[0][tid] + red[1][tid] + red[2][tid] + red[3][tid];
        e_out[b * T_ + t0 + tid] = e;
    }
}

// ---------------------------------------------------------------------------
// Softmax over T per batch + new_coverage.
__global__ __launch_bounds__(256) void k_soft(const float* __restrict__ e_in,
                                              const float* __restrict__ coverage,
                                              float* __restrict__ out_at,
                                              float* __restrict__ out_cov) {
    int b = blockIdx.x, tid = threadIdx.x;
    __shared__ float red[4];
    float v[16];
    float m = -1e30f;
#pragma unroll
    for (int i = 0; i < 16; ++i) {
        v[i] = e_in[b * T_ + tid + i * 256];
        m = fmaxf(m, v[i]);
    }
#pragma unroll
    for (int mk = 1; mk <= 32; mk <<= 1) m = fmaxf(m, __shfl_xor(m, mk, 64));
    if ((tid & 63) == 0) red[tid >> 6] = m;
    __syncthreads();
    m = fmaxf(fmaxf(red[0], red[1]), fmaxf(red[2], red[3]));
    float s = 0.f;
#pragma unroll
    for (int i = 0; i < 16; ++i) { v[i] = expf(v[i] - m); s += v[i]; }
#pragma unroll
    for (int mk = 1; mk <= 32; mk <<= 1) s += __shfl_xor(s, mk, 64);
    __syncthreads();
    if ((tid & 63) == 0) red[tid >> 6] = s;
    __syncthreads();
    s = red[0] + red[1] + red[2] + red[3];
    float inv = 1.0f / s;
#pragma unroll
    for (int i = 0; i < 16; ++i) {
        int idx = b * T_ + tid + i * 256;
        float a = v[i] * inv;
        out_at[idx]  = a;
        out_cov[idx] = coverage[idx] + a;
    }
}

// ---------------------------------------------------------------------------
// context partials
__global__ __launch_bounds__(256) void k_ctx(const float* __restrict__ h_i,
                                             const float* __restrict__ a_t,
                                             float* __restrict__ part) {
    int blk = blockIdx.x;           // 0..2047
    int b = blk >> 6, s = blk & 63;
    int d0 = threadIdx.x * 2;
    const size_t base = ((size_t)b * T_ + (size_t)s * 64) * D_;
    const float* at = a_t + b * T_ + s * 64;
    float2 acc = {0.f, 0.f};
    for (int t = 0; t < 64; ++t) {
        float a = at[t];
        float2 h2 = *(const float2*)(h_i + base + (size_t)t * D_ + d0);
        acc.x = fmaf(a, h2.x, acc.x);
        acc.y = fmaf(a, h2.y, acc.y);
    }
    float* pp = part + (size_t)blk * D_ + d0;
    pp[0] = acc.x;
    pp[1] = acc.y;
}

__global__ __launch_bounds__(256) void k_comb(const float* __restrict__ part,
                                              float* __restrict__ out_ctx) {
    int idx = blockIdx.x * 256 + threadIdx.x;   // 0..16383
    int b = idx >> 9, d = idx & 511;
    const float* pp = part + (size_t)b * 64 * D_ + d;
    float s = 0.f;
#pragma unroll 8
    for (int j = 0; j < 64; ++j) s += pp[(size_t)j * D_];
    out_ctx[idx] = s;
}

// ---------------------------------------------------------------------------
extern "C" void kernel_launch(void* const* d_in, const int* in_sizes, int n_in,
                              void* d_out, int out_size, void* d_ws, size_t ws_size,
                              hipStream_t stream) {
    const float* h_i      = (const float*)d_in[0];
    const float* s_t      = (const float*)d_in[1];
    const float* coverage = (const float*)d_in[2];
    const float* W_h      = (const float*)d_in[3];
    const float* W_s      = (const float*)d_in[4];
    const float* b_s      = (const float*)d_in[5];
    const float* W_c      = (const float*)d_in[6];
    const float* V        = (const float*)d_in[7];

    float* out_ctx = (float*)d_out;             // B*D
    float* out_at  = out_ctx + B_ * D_;         // B*T (holds e_t between k_main and k_soft)
    float* out_cov = out_at + BT_;              // B*T

    unsigned short* wsb = (unsigned short*)d_ws;              // 512 KB bf16 W_h frags
    float* dec  = (float*)((char*)d_ws + 524288);             // 64 KB
    float* part = dec + B_ * D_;                              // 4 MB

    k_conv_wh<<<128, 256, 0, stream>>>(W_h, wsb);
    k_dec<<<B_, 256, 0, stream>>>(s_t, W_s, b_s, dec);
    k_main<<<BT_ / 64, 256, 0, stream>>>(h_i, coverage, wsb, dec, W_c, V, out_at);
    k_soft<<<B_, 256, 0, stream>>>(out_at, coverage, out_at, out_cov);
    k_ctx<<<B_ * 64, 256, 0, stream>>>(h_i, out_at, part);
    k_comb<<<B_ * D_ / 256, 256, 0, stream>>>(part, out_ctx);
}

// Round 3
// 196.082 us; speedup vs baseline: 1.6998x; 1.0407x over previous
//
#include <hip/hip_runtime.h>
#include <stdint.h>

#define B_ 32
#define T_ 4096
#define D_ 512
#define BT_ (B_*T_)

typedef __attribute__((ext_vector_type(8))) short bf16x8;
typedef __attribute__((ext_vector_type(4))) float f32x4;

__device__ __forceinline__ unsigned short f2bf(float f) {
    unsigned int u = __float_as_uint(f);
    u += 0x7FFFu + ((u >> 16) & 1u);   // round-to-nearest-even (inputs are finite)
    return (unsigned short)(u >> 16);
}

__device__ __forceinline__ float tanh_fast(float x) {
    float e2 = __expf(2.0f * x);       // inf for large x, 0 for very negative -> correct limits
    return 1.0f - 2.0f / (e2 + 1.0f);
}

// ---------------------------------------------------------------------------
// W_h (D x D fp32, [k][n]) -> bf16 MFMA B-fragment layout in ws:
//   wsb[((nt*16+kt)*64 + l)*8 + j] = bf16(W_h[kt*32 + (l>>4)*8 + j][nt*16 + (l&15)])
__global__ __launch_bounds__(256) void k_conv_wh(const float* __restrict__ W_h,
                                                 unsigned short* __restrict__ wsb) {
    int tid = blockIdx.x * 256 + threadIdx.x;   // 0..32767
    int l  = tid & 63;
    int kt = (tid >> 6) & 15;
    int nt = tid >> 10;
    int n  = nt * 16 + (l & 15);
    int k0 = kt * 32 + (l >> 4) * 8;
    unsigned int w[4];
#pragma unroll
    for (int q = 0; q < 4; ++q) {
        unsigned short lo = f2bf(W_h[(size_t)(k0 + 2*q)     * D_ + n]);
        unsigned short hi = f2bf(W_h[(size_t)(k0 + 2*q + 1) * D_ + n]);
        w[q] = (unsigned int)lo | ((unsigned int)hi << 16);
    }
    uint4 pk = {w[0], w[1], w[2], w[3]};
    ((uint4*)wsb)[tid] = pk;
}

// ---------------------------------------------------------------------------
// dec[b][c] = b_s[c] + sum_k s_t[b][k] * W_s[k][c]
__global__ __launch_bounds__(256) void k_dec(const float* __restrict__ s_t,
                                             const float* __restrict__ W_s,
                                             const float* __restrict__ b_s,
                                             float* __restrict__ dec) {
    int b = blockIdx.x;
    int c = threadIdx.x;
    float a0 = b_s[c], a1 = b_s[c + 256];
    const float* srow = s_t + b * D_;
    for (int k = 0; k < D_; ++k) {
        float s = srow[k];
        const float* wr = W_s + (size_t)k * D_;
        a0 = fmaf(s, wr[c], a0);
        a1 = fmaf(s, wr[c + 256], a1);
    }
    dec[b * D_ + c] = a0;
    dec[b * D_ + c + 256] = a1;
}

// ---------------------------------------------------------------------------
// Main fused kernel. Block = 64 rows of (B*T), 8 waves (512 threads).
// A panel (64 rows x 512 K, bf16) staged once in LDS, shared by all 8 waves.
// Wave w computes output cols [w*64, w*64+64).
// LDS: frag (af,kt) base = (af*16+kt)*1024; element-for-lane-lam stored at
// slot sigma(lam,kt) = (lam&0x38) | ((lam&7) ^ ((lam>>4&3)<<1) ^ (kt&1)).
// Write side: per 8-lane phase group slot&7 = (row&7)^((l&3)<<1|(l>>2&1)),
// all 8 distinct -> conflict-free. Read side: bijection of contiguous 1KB
// -> conflict-free. Same mapping both sides.
__global__ __launch_bounds__(512, 4) void k_main(const float* __restrict__ h_i,
                                                 const float* __restrict__ coverage,
                                                 const unsigned short* __restrict__ wsb,
                                                 const float* __restrict__ dec,
                                                 const float* __restrict__ W_c,
                                                 const float* __restrict__ V,
                                                 float* __restrict__ e_out) {
    __shared__ __align__(16) unsigned char As[65536];
    __shared__ float red[8][64];
    const int tid = threadIdx.x;
    const int w = tid >> 6, l = tid & 63;
    const int row0 = blockIdx.x * 64;           // flat (b*T + t), 64-aligned
    const int b    = row0 >> 12;
    const int t0   = row0 & (T_ - 1);

    // ---- stage A: 64 rows x 512 k, fp32 -> bf16, sigma-swizzled fragment layout
#pragma unroll
    for (int i = 0; i < 8; ++i) {
        int row = i * 8 + w;                    // one row per wave per iter
        const float* src = h_i + (size_t)(row0 + row) * D_ + l * 8;
        float4 f0 = *(const float4*)(src);
        float4 f1 = *(const float4*)(src + 4);
        uint4 pk;
        pk.x = (unsigned)f2bf(f0.x) | ((unsigned)f2bf(f0.y) << 16);
        pk.y = (unsigned)f2bf(f0.z) | ((unsigned)f2bf(f0.w) << 16);
        pk.z = (unsigned)f2bf(f1.x) | ((unsigned)f2bf(f1.y) << 16);
        pk.w = (unsigned)f2bf(f1.z) | ((unsigned)f2bf(f1.w) << 16);
        int kt   = l >> 2;
        int lam  = (row & 15) + 16 * (l & 3);
        int slot = (lam & 0x38) | ((lam & 7) ^ ((l & 3) << 1) ^ (kt & 1));
        int byte = (((row >> 4) * 16 + kt) << 10) + (slot << 4);
        *(uint4*)(As + byte) = pk;
    }
    __syncthreads();

    // read slot for this lane (kt-even base; XOR 1 for odd kt)
    const int slotR = (l & 0x38) | ((l & 7) ^ (((l >> 4) & 3) << 1));

    f32x4 acc[4][4];                            // [af][j]
#pragma unroll
    for (int af = 0; af < 4; ++af)
#pragma unroll
        for (int j = 0; j < 4; ++j) acc[af][j] = (f32x4){0, 0, 0, 0};

    const uint4* bw = (const uint4*)wsb + ((w * 4) << 10) + l;   // ((w*4+j)*16+kt)*64+l

#pragma unroll 4
    for (int kt = 0; kt < 16; ++kt) {
        bf16x8 bv[4];
#pragma unroll
        for (int j = 0; j < 4; ++j) {
            uint4 braw = bw[(j << 10) + (kt << 6)];
            bv[j] = __builtin_bit_cast(bf16x8, braw);
        }
        int sl = (slotR ^ (kt & 1)) << 4;
#pragma unroll
        for (int af = 0; af < 4; ++af) {
            int byte = ((af * 16 + kt) << 10) + sl;
            uint4 araw = *(const uint4*)(As + byte);
            bf16x8 a = __builtin_bit_cast(bf16x8, araw);
#pragma unroll
            for (int j = 0; j < 4; ++j)
                acc[af][j] = __builtin_amdgcn_mfma_f32_16x16x32_bf16(a, bv[j], acc[af][j], 0, 0, 0);
        }
    }

    // ---- epilogue: tanh + dot with V over this wave's 64 cols
    const int rgrp = (l >> 4) * 4;
    float cov_r[4][4];
#pragma unroll
    for (int af = 0; af < 4; ++af)
#pragma unroll
        for (int r = 0; r < 4; ++r)
            cov_r[af][r] = coverage[b * T_ + t0 + af * 16 + rgrp + r];

    float p[4][4] = {{0,0,0,0},{0,0,0,0},{0,0,0,0},{0,0,0,0}};  // [af][r]
#pragma unroll
    for (int j = 0; j < 4; ++j) {
        int col = w * 64 + j * 16 + (l & 15);
        float dv = dec[b * D_ + col];
        float wc = W_c[col];
        float vv = V[col];
#pragma unroll
        for (int af = 0; af < 4; ++af)
#pragma unroll
            for (int r = 0; r < 4; ++r) {
                float x = acc[af][j][r] + dv + cov_r[af][r] * wc;
                p[af][r] += tanh_fast(x) * vv;
            }
    }

    // reduce across the 16 lanes sharing each row (lane bits 0..3)
#pragma unroll
    for (int m = 1; m <= 8; m <<= 1)
#pragma unroll
        for (int af = 0; af < 4; ++af)
#pragma unroll
            for (int r = 0; r < 4; ++r)
                p[af][r] += __shfl_xor(p[af][r], m, 64);
    if ((l & 15) == 0) {
#pragma unroll
        for (int af = 0; af < 4; ++af)
#pragma unroll
            for (int r = 0; r < 4; ++r)
                red[w][af * 16 + rgrp + r] = p[af][r];
    }
    __syncthreads();
    if (tid < 64) {
        float e = red[0][tid] + red[1][tid] + red[2][tid] + red[3][tid]
                + red[4][tid] + red[5][tid] + red[6][tid] + red[7][tid];
        e_out[b * T_ + t0 + tid] = e;
    }
}

// ---------------------------------------------------------------------------
// Softmax over T per batch + new_coverage.
__global__ __launch_bounds__(256) void k_soft(const float* __restrict__ e_in,
                                              const float* __restrict__ coverage,
                                              float* __restrict__ out_at,
                                              float* __restrict__ out_cov) {
    int b = blockIdx.x, tid = threadIdx.x;
    __shared__ float red[4];
    float v[16];
    float m = -1e30f;
#pragma unroll
    for (int i = 0; i < 16; ++i) {
        v[i] = e_in[b * T_ + tid + i * 256];
        m = fmaxf(m, v[i]);
    }
#pragma unroll
    for (int mk = 1; mk <= 32; mk <<= 1) m = fmaxf(m, __shfl_xor(m, mk, 64));
    if ((tid & 63) == 0) red[tid >> 6] = m;
    __syncthreads();
    m = fmaxf(fmaxf(red[0], red[1]), fmaxf(red[2], red[3]));
    float s = 0.f;
#pragma unroll
    for (int i = 0; i < 16; ++i) { v[i] = expf(v[i] - m); s += v[i]; }
#pragma unroll
    for (int mk = 1; mk <= 32; mk <<= 1) s += __shfl_xor(s, mk, 64);
    __syncthreads();
    if ((tid & 63) == 0) red[tid >> 6] = s;
    __syncthreads();
    s = red[0] + red[1] + red[2] + red[3];
    float inv = 1.0f / s;
#pragma unroll
    for (int i = 0; i < 16; ++i) {
        int idx = b * T_ + tid + i * 256;
        float a = v[i] * inv;
        out_at[idx]  = a;
        out_cov[idx] = coverage[idx] + a;
    }
}

// ---------------------------------------------------------------------------
// context partials
__global__ __launch_bounds__(256) void k_ctx(const float* __restrict__ h_i,
                                             const float* __restrict__ a_t,
                                             float* __restrict__ part) {
    int blk = blockIdx.x;           // 0..2047
    int b = blk >> 6, s = blk & 63;
    int d0 = threadIdx.x * 2;
    const size_t base = ((size_t)b * T_ + (size_t)s * 64) * D_;
    const float* at = a_t + b * T_ + s * 64;
    float2 acc = {0.f, 0.f};
    for (int t = 0; t < 64; ++t) {
        float a = at[t];
        float2 h2 = *(const float2*)(h_i + base + (size_t)t * D_ + d0);
        acc.x = fmaf(a, h2.x, acc.x);
        acc.y = fmaf(a, h2.y, acc.y);
    }
    float* pp = part + (size_t)blk * D_ + d0;
    pp[0] = acc.x;
    pp[1] = acc.y;
}

__global__ __launch_bounds__(256) void k_comb(const float* __restrict__ part,
                                              float* __restrict__ out_ctx) {
    int idx = blockIdx.x * 256 + threadIdx.x;   // 0..16383
    int b = idx >> 9, d = idx & 511;
    const float* pp = part + (size_t)b * 64 * D_ + d;
    float s = 0.f;
#pragma unroll 8
    for (int j = 0; j < 64; ++j) s += pp[(size_t)j * D_];
    out_ctx[idx] = s;
}

// ---------------------------------------------------------------------------
extern "C" void kernel_launch(void* const* d_in, const int* in_sizes, int n_in,
                              void* d_out, int out_size, void* d_ws, size_t ws_size,
                              hipStream_t stream) {
    const float* h_i      = (const float*)d_in[0];
    const float* s_t      = (const float*)d_in[1];
    const float* coverage = (const float*)d_in[2];
    const float* W_h      = (const float*)d_in[3];
    const float* W_s      = (const float*)d_in[4];
    const float* b_s      = (const float*)d_in[5];
    const float* W_c      = (const float*)d_in[6];
    const float* V        = (const float*)d_in[7];

    float* out_ctx = (float*)d_out;             // B*D
    float* out_at  = out_ctx + B_ * D_;         // B*T (holds e_t between k_main and k_soft)
    float* out_cov = out_at + BT_;              // B*T

    unsigned short* wsb = (unsigned short*)d_ws;              // 512 KB bf16 W_h frags
    float* dec  = (float*)((char*)d_ws + 524288);             // 64 KB
    float* part = dec + B_ * D_;                              // 4 MB

    k_conv_wh<<<128, 256, 0, stream>>>(W_h, wsb);
    k_dec<<<B_, 256, 0, stream>>>(s_t, W_s, b_s, dec);
    k_main<<<BT_ / 64, 512, 0, stream>>>(h_i, coverage, wsb, dec, W_c, V, out_at);
    k_soft<<<B_, 256, 0, stream>>>(out_at, coverage, out_at, out_cov);
    k_ctx<<<B_ * 64, 256, 0, stream>>>(h_i, out_at, part);
    k_comb<<<B_ * D_ / 256, 256, 0, stream>>>(part, out_ctx);
}